// Round 1
// baseline (2990.017 us; speedup 1.0000x reference)
//
#include <hip/hip_runtime.h>
#include <hip/hip_bf16.h>

// WaveNet on MI355X — round 0: fp32 VALU baseline, restructured skip path.
//
// Index convention: all sequence buffers are indexed by ORIGINAL position
// p in [0, 8192). Layer i (dilation d) output at p reads h[p-d], h[p];
// valid outputs are p >= pmin_out (pmin grows by d each layer, max 4092).
// Output needs only p in [4096, 8192) -> skip contributions stored as z
// (bf16) and reduced with one big GEMM instead of 40 RMW passes.
//
// Workspace layout (needs ~171 MB):
//   h0, h1 : 2 x 8*32*8192 f32   = 16.8 MB  (double-buffered residual h)
//   Z      : 40*8*32*4096 bf16   = 83.9 MB  (gated activations, p>=4096)
//   skipb  : 8*512*4096 f32      = 67.1 MB  (relu'd skip accumulator)
//   wskT   : 1280*512 f32        = 2.6 MB   (skip weights transposed [q][s])
//   ewT    : 512*256 f32         = 0.5 MB   (end weights transposed [s][cls])

#define BATCH   8
#define SEQ     8192
#define RES_CH  32
#define DIL_CH  32
#define SKIP_CH 512
#define CLASSES 256
#define NLAYERS 40
#define OUTLEN  4096
#define PSTART  (SEQ - OUTLEN)   // 4096
#define PT      16               // positions per thread in k_end

__device__ __forceinline__ float fast_sigmoid(float x) {
    return __builtin_amdgcn_rcpf(1.0f + __expf(-x));
}
__device__ __forceinline__ float fast_tanh(float x) {
    // tanh(x) = 1 - 2/(exp(2x)+1); robust at +-inf (exp->inf gives 1, exp->0 gives -1)
    return 1.0f - 2.0f * __builtin_amdgcn_rcpf(1.0f + __expf(2.0f * x));
}

// h[b][c][p] = x[b][p] * start_w[c]
__global__ __launch_bounds__(256) void k_init(const float* __restrict__ x,
                                              const float* __restrict__ sw,
                                              float* __restrict__ h) {
    int idx = blockIdx.x * 256 + threadIdx.x;   // over BATCH*SEQ
    if (idx >= BATCH * SEQ) return;
    int b = idx / SEQ, p = idx % SEQ;
    float v = x[idx];
#pragma unroll
    for (int c = 0; c < RES_CH; ++c)
        h[((size_t)b * RES_CH + c) * SEQ + p] = v * sw[c];
}

// wskT[q=i*32+o][s] = skip_w[i][s][o]
__global__ __launch_bounds__(256) void k_transpose_wsk(const float* __restrict__ wsk,
                                                       float* __restrict__ wskT) {
    int idx = blockIdx.x * 256 + threadIdx.x;   // 40*512*32
    if (idx >= NLAYERS * SKIP_CH * DIL_CH) return;
    int o = idx % DIL_CH;
    int s = (idx / DIL_CH) % SKIP_CH;
    int i = idx / (DIL_CH * SKIP_CH);
    wskT[((size_t)i * DIL_CH + o) * SKIP_CH + s] = wsk[idx];
}

// ewT[s][cls] = end_w[cls][s]
__global__ __launch_bounds__(256) void k_transpose_ew(const float* __restrict__ ew,
                                                      float* __restrict__ ewT) {
    int idx = blockIdx.x * 256 + threadIdx.x;   // 256*512
    if (idx >= CLASSES * SKIP_CH) return;
    int s = idx % SKIP_CH;
    int c = idx / SKIP_CH;
    ewT[(size_t)s * CLASSES + c] = ew[idx];
}

// One WaveNet layer: z = tanh(Wf*h2)*sigmoid(Wg*h2); h' = Wr*z + h; stash z(bf16).
// Weights are read with wave-uniform indices -> scalar loads (constant cache),
// h/z live in registers (all loops fully unrolled => static indexing).
__global__ __launch_bounds__(256) void k_layer(
    const float* __restrict__ hin, float* __restrict__ hout,
    const float* __restrict__ fw, const float* __restrict__ gw,
    const float* __restrict__ rw, __hip_bfloat16* __restrict__ Z,
    int layer, int d, int pmin_out)
{
    int p = pmin_out + blockIdx.x * 256 + threadIdx.x;
    if (p >= SEQ) return;
    const int b = blockIdx.y;
    const float* hb = hin + (size_t)b * RES_CH * SEQ;

    float hm[RES_CH], h1[RES_CH];
#pragma unroll
    for (int c = 0; c < RES_CH; ++c) {
        hm[c] = hb[c * SEQ + (p - d)];
        h1[c] = hb[c * SEQ + p];
    }

    const float* fwl = fw + (size_t)layer * DIL_CH * RES_CH * 2;
    const float* gwl = gw + (size_t)layer * DIL_CH * RES_CH * 2;

    float z[DIL_CH];
#pragma unroll
    for (int o = 0; o < DIL_CH; ++o) {
        float af = 0.f, ag = 0.f;
#pragma unroll
        for (int c = 0; c < RES_CH; ++c) {
            float f0 = fwl[(o * RES_CH + c) * 2 + 0];
            float f1 = fwl[(o * RES_CH + c) * 2 + 1];
            af += f0 * hm[c] + f1 * h1[c];
            float g0 = gwl[(o * RES_CH + c) * 2 + 0];
            float g1 = gwl[(o * RES_CH + c) * 2 + 1];
            ag += g0 * hm[c] + g1 * h1[c];
        }
        z[o] = fast_tanh(af) * fast_sigmoid(ag);
    }

    const float* rwl = rw + (size_t)layer * RES_CH * DIL_CH;
    float* hob = hout + (size_t)b * RES_CH * SEQ;
#pragma unroll
    for (int c = 0; c < RES_CH; ++c) {
        float acc = h1[c];
#pragma unroll
        for (int o = 0; o < DIL_CH; ++o)
            acc += rwl[c * DIL_CH + o] * z[o];
        hob[c * SEQ + p] = acc;
    }

    if (p >= PSTART) {
        int p4 = p - PSTART;
        __hip_bfloat16* zb = Z + ((size_t)layer * BATCH + b) * DIL_CH * OUTLEN + p4;
#pragma unroll
        for (int o = 0; o < DIL_CH; ++o)
            zb[(size_t)o * OUTLEN] = __float2bfloat16(z[o]);
    }
}

// skip[b][s][p] = relu( sum_q wskT[q][s] * Z[q][b][p] ), q = layer*32+o
// Block: 64 s-outputs x 256 positions; weights scalarize (uniform per block).
__global__ __launch_bounds__(256) void k_skip(
    const __hip_bfloat16* __restrict__ Z, const float* __restrict__ wskT,
    float* __restrict__ skipb)
{
    const int s0 = blockIdx.x * 64;
    const int p4 = blockIdx.y * 256 + threadIdx.x;
    const int b  = blockIdx.z;

    float acc[64];
#pragma unroll
    for (int j = 0; j < 64; ++j) acc[j] = 0.f;

    const __hip_bfloat16* zb = Z + (size_t)b * DIL_CH * OUTLEN + p4;
#pragma unroll 2
    for (int q = 0; q < NLAYERS * DIL_CH; ++q) {
        int i = q >> 5, o = q & 31;
        float zv = __bfloat162float(zb[((size_t)i * BATCH * DIL_CH + o) * OUTLEN]);
        const float* w = wskT + (size_t)q * SKIP_CH + s0;
#pragma unroll
        for (int j = 0; j < 64; ++j) acc[j] += w[j] * zv;
    }

    float* sk = skipb + ((size_t)b * SKIP_CH + s0) * OUTLEN + p4;
#pragma unroll
    for (int j = 0; j < 64; ++j)
        sk[(size_t)j * OUTLEN] = fmaxf(acc[j], 0.f);   // relu folded into store
}

// out[(b*4096+t)*256 + cls] = sum_s ewT[s][cls] * skip[b][s][t] + eb[cls]
__global__ __launch_bounds__(256) void k_end(
    const float* __restrict__ skipb, const float* __restrict__ ewT,
    const float* __restrict__ eb, float* __restrict__ out)
{
    const int cls = threadIdx.x;      // 256 classes
    const int p0  = blockIdx.x * PT;
    const int b   = blockIdx.y;

    float acc[PT];
#pragma unroll
    for (int j = 0; j < PT; ++j) acc[j] = 0.f;

    const float* skb = skipb + (size_t)b * SKIP_CH * OUTLEN + p0;
#pragma unroll 4
    for (int s = 0; s < SKIP_CH; ++s) {
        float w = ewT[(size_t)s * CLASSES + cls];
#pragma unroll
        for (int j = 0; j < PT; ++j)
            acc[j] += w * skb[(size_t)s * OUTLEN + j];   // skip loads are scalar (uniform)
    }

    float bias = eb[cls];
#pragma unroll
    for (int j = 0; j < PT; ++j)
        out[((size_t)b * OUTLEN + p0 + j) * CLASSES + cls] = acc[j] + bias;
}

extern "C" void kernel_launch(void* const* d_in, const int* in_sizes, int n_in,
                              void* d_out, int out_size, void* d_ws, size_t ws_size,
                              hipStream_t stream) {
    const float* x   = (const float*)d_in[0];
    const float* sw  = (const float*)d_in[1];
    const float* fw  = (const float*)d_in[2];
    const float* gw  = (const float*)d_in[3];
    const float* rw  = (const float*)d_in[4];
    const float* wsk = (const float*)d_in[5];
    const float* ew  = (const float*)d_in[6];
    const float* eb  = (const float*)d_in[7];
    float* out = (float*)d_out;

    float* h0 = (float*)d_ws;
    float* h1 = h0 + (size_t)BATCH * RES_CH * SEQ;
    __hip_bfloat16* Z = (__hip_bfloat16*)(h1 + (size_t)BATCH * RES_CH * SEQ);
    float* skipb = (float*)(Z + (size_t)NLAYERS * BATCH * DIL_CH * OUTLEN);
    float* wskT  = skipb + (size_t)BATCH * SKIP_CH * OUTLEN;
    float* ewT   = wskT + (size_t)NLAYERS * DIL_CH * SKIP_CH;
    // total ws use: 170,917,888 bytes

    k_init<<<dim3((BATCH * SEQ + 255) / 256), 256, 0, stream>>>(x, sw, h0);
    k_transpose_wsk<<<dim3((NLAYERS * SKIP_CH * DIL_CH + 255) / 256), 256, 0, stream>>>(wsk, wskT);
    k_transpose_ew<<<dim3((CLASSES * SKIP_CH + 255) / 256), 256, 0, stream>>>(ew, ewT);

    float* hbuf[2] = {h0, h1};
    int pmin = 0, cur = 0;
    for (int i = 0; i < NLAYERS; ++i) {
        int d = 1 << (i % 10);            // DILATIONS = [1..512] x 4
        int pmin_out = pmin + d;
        int Lp = SEQ - pmin_out;
        dim3 g((Lp + 255) / 256, BATCH);
        k_layer<<<g, 256, 0, stream>>>(hbuf[cur], hbuf[cur ^ 1], fw, gw, rw, Z,
                                       i, d, pmin_out);
        cur ^= 1;
        pmin = pmin_out;
    }

    k_skip<<<dim3(SKIP_CH / 64, OUTLEN / 256, BATCH), 256, 0, stream>>>(Z, wskT, skipb);
    k_end<<<dim3(OUTLEN / PT, BATCH), 256, 0, stream>>>(skipb, ewT, eb, out);
}

// Round 2
// 980.781 us; speedup vs baseline: 3.0486x; 3.0486x over previous
//
#include <hip/hip_runtime.h>
#include <hip/hip_bf16.h>

// WaveNet on MI355X — round 2: MFMA skip/end GEMMs + occupancy-fixed layers.
//
// Buffers (all indexed by ORIGINAL position p in [0,8192)):
//   h0,h1  : [b][c][p] f32 (double-buffered residual)
//   Z      : [b][p4][q] bf16, q = layer*32+o, p4 = p-4096  (k-contiguous for MFMA)
//   skipb  : [b][p4][s] bf16 (relu already applied)
//   wskB   : bf16 copy of skip_w [i][s][o]  (A-operand, k(=i,o)-contiguous per i)
//   ewB    : bf16 copy of end_w  [cls][s]   (A-operand, k(=s)-contiguous)

#define BATCH   8
#define SEQ     8192
#define RES_CH  32
#define DIL_CH  32
#define SKIP_CH 512
#define CLASSES 256
#define NLAYERS 40
#define OUTLEN  4096
#define PSTART  (SEQ - OUTLEN)   // 4096
#define QTOT    (NLAYERS * DIL_CH)  // 1280

typedef __attribute__((ext_vector_type(8))) short bf16x8;
typedef __attribute__((ext_vector_type(4))) short short4_t;
typedef __attribute__((ext_vector_type(8))) short short8_t;
typedef __attribute__((ext_vector_type(4))) float f32x4;

__device__ __forceinline__ float fast_sigmoid(float x) {
    return __builtin_amdgcn_rcpf(1.0f + __expf(-x));
}
__device__ __forceinline__ float fast_tanh(float x) {
    return 1.0f - 2.0f * __builtin_amdgcn_rcpf(1.0f + __expf(2.0f * x));
}
// f32 -> bf16 bits, round-to-nearest-even
__device__ __forceinline__ short f2bf(float x) {
    unsigned u = __float_as_uint(x);
    unsigned r = (u + 0x7fffu + ((u >> 16) & 1u)) >> 16;
    return (short)r;
}
__device__ __forceinline__ float bf2f(short s) {
    unsigned u = ((unsigned)(unsigned short)s) << 16;
    return __uint_as_float(u);
}

// h[b][c][p] = x[b][p] * start_w[c]
__global__ __launch_bounds__(256) void k_init(const float* __restrict__ x,
                                              const float* __restrict__ sw,
                                              float* __restrict__ h) {
    int idx = blockIdx.x * 256 + threadIdx.x;
    if (idx >= BATCH * SEQ) return;
    int b = idx / SEQ, p = idx % SEQ;
    float v = x[idx];
#pragma unroll
    for (int c = 0; c < RES_CH; ++c)
        h[((size_t)b * RES_CH + c) * SEQ + p] = v * sw[c];
}

// generic f32 -> bf16 convert
__global__ __launch_bounds__(256) void k_cvt(const float* __restrict__ src,
                                             short* __restrict__ dst, int n) {
    int i = blockIdx.x * 256 + threadIdx.x;
    if (i < n) dst[i] = f2bf(src[i]);
}

// One WaveNet layer. Block = 64 positions x 4 channel-groups (256 thr).
// Each thread: 8 f-outputs + 8 g-outputs (weights wave-uniform -> s_load),
// z shared via LDS for the res conv, z also stored to Z[b][p4][q] (bf16).
__global__ __launch_bounds__(256) void k_layer2(
    const float* __restrict__ hin, float* __restrict__ hout,
    const float* __restrict__ fw, const float* __restrict__ gw,
    const float* __restrict__ rw, short* __restrict__ Z,
    int layer, int d, int pmin_out)
{
    __shared__ float zt[64][33];
    const int pos_i = threadIdx.x & 63;
    const int grp   = threadIdx.x >> 6;                       // 0..3
    const int grp_u = __builtin_amdgcn_readfirstlane(grp);    // provably uniform
    const int p = pmin_out + blockIdx.x * 64 + pos_i;
    const int b = blockIdx.y;
    const bool valid = p < SEQ;

    const float* hb = hin + (size_t)b * RES_CH * SEQ;
    float hm[RES_CH], h1[RES_CH];
    if (valid) {
#pragma unroll
        for (int c = 0; c < RES_CH; ++c) {
            hm[c] = hb[c * SEQ + (p - d)];
            h1[c] = hb[c * SEQ + p];
        }
    } else {
#pragma unroll
        for (int c = 0; c < RES_CH; ++c) { hm[c] = 0.f; h1[c] = 0.f; }
    }

    // weights for this group's 8 outputs: fw[layer][o][c][tap], o = grp*8+j
    const float* fwl = fw + (size_t)layer * 2048 + grp_u * 512;
    const float* gwl = gw + (size_t)layer * 2048 + grp_u * 512;

    float z[8];
#pragma unroll
    for (int j = 0; j < 8; ++j) {
        const float* fj_ = fwl + j * 64;   // 64 consecutive f32 (c,tap)
        const float* gj_ = gwl + j * 64;
        float af = 0.f, ag = 0.f;
#pragma unroll
        for (int c = 0; c < RES_CH; ++c) {
            float f0 = fj_[2 * c], f1 = fj_[2 * c + 1];
            float g0 = gj_[2 * c], g1 = gj_[2 * c + 1];
            af = fmaf(f0, hm[c], fmaf(f1, h1[c], af));
            ag = fmaf(g0, hm[c], fmaf(g1, h1[c], ag));
        }
        z[j] = fast_tanh(af) * fast_sigmoid(ag);
    }

#pragma unroll
    for (int j = 0; j < 8; ++j) zt[pos_i][grp * 8 + j] = z[j];

    // stash z to global (bf16, only p >= 4096), one 16B store
    if (valid && p >= PSTART) {
        short8_t v;
#pragma unroll
        for (int j = 0; j < 8; ++j) v[j] = f2bf(z[j]);
        *(short8_t*)(Z + ((size_t)b * OUTLEN + (p - PSTART)) * QTOT
                       + layer * DIL_CH + grp * 8) = v;
    }

    __syncthreads();

    // res conv: h'[c] = h[c] + sum_o rw[c][o] * z[o], c in [grp*8, grp*8+8)
    float zv[DIL_CH];
#pragma unroll
    for (int o = 0; o < DIL_CH; ++o) zv[o] = zt[pos_i][o];   // conflict-free (pad 33)

    const float* rwl = rw + (size_t)layer * 1024 + grp_u * 256;  // [c][o], 8 rows
    float* hob = hout + (size_t)b * RES_CH * SEQ;
    if (valid) {
#pragma unroll
        for (int jc = 0; jc < 8; ++jc) {
            int c = grp * 8 + jc;
            float acc = hb[c * SEQ + p];   // reload tap-1 (L1 hot); avoids dyn reg idx
#pragma unroll
            for (int o = 0; o < DIL_CH; ++o)
                acc = fmaf(rwl[jc * 32 + o], zv[o], acc);
            hob[c * SEQ + p] = acc;
        }
    }
}

// skip GEMM: C[s][p] = sum_q wskB[s][q] * Z[b][p][q], relu, store bf16 [b][p][s].
// 512 thr = 8 waves (2 s x 4 p), block tile 128(s) x 256(p), K = 1280.
__global__ __launch_bounds__(512, 4) void k_skip_mfma(
    const short* __restrict__ Z, const short* __restrict__ wskB,
    short* __restrict__ skipb)
{
    const int lane = threadIdx.x & 63;
    const int w    = threadIdx.x >> 6;
    const int wr   = w >> 2;            // 0..1
    const int wc   = w & 3;             // 0..3
    const int s0 = blockIdx.x * 128 + wr * 64;
    const int p0 = blockIdx.y * 256 + wc * 64;
    const int b  = blockIdx.z;

    const int r = lane & 15;
    const int g = lane >> 4;

    const short* Zb = Z + (size_t)b * OUTLEN * QTOT;

    // 32-bit offsets from uniform bases -> saddr+voffset loads
    int aoff[4], boff[4];
#pragma unroll
    for (int fi = 0; fi < 4; ++fi)
        aoff[fi] = (s0 + fi * 16 + r) * 32 + g * 8;     // + kt*16384 per step
#pragma unroll
    for (int fj = 0; fj < 4; ++fj)
        boff[fj] = (p0 + fj * 16 + r) * QTOT + g * 8;   // + kt*32 per step

    f32x4 acc[4][4];
    const f32x4 zero4 = {0.f, 0.f, 0.f, 0.f};
#pragma unroll
    for (int fi = 0; fi < 4; ++fi)
#pragma unroll
        for (int fj = 0; fj < 4; ++fj) acc[fi][fj] = zero4;

    for (int kt = 0; kt < QTOT / 32; ++kt) {
        bf16x8 av[4], bv[4];
#pragma unroll
        for (int fi = 0; fi < 4; ++fi)
            av[fi] = *(const bf16x8*)(wskB + aoff[fi] + kt * (SKIP_CH * 32));
#pragma unroll
        for (int fj = 0; fj < 4; ++fj)
            bv[fj] = *(const bf16x8*)(Zb + boff[fj] + kt * 32);
#pragma unroll
        for (int fi = 0; fi < 4; ++fi)
#pragma unroll
            for (int fj = 0; fj < 4; ++fj)
                acc[fi][fj] = __builtin_amdgcn_mfma_f32_16x16x32_bf16(
                    av[fi], bv[fj], acc[fi][fj], 0, 0, 0);
    }

    // D: row(s) = (lane>>4)*4+reg, col(p) = lane&15. 4 rows contiguous in s.
    short* skb = skipb + (size_t)b * OUTLEN * SKIP_CH;
#pragma unroll
    for (int fj = 0; fj < 4; ++fj) {
        int p = p0 + fj * 16 + r;
#pragma unroll
        for (int fi = 0; fi < 4; ++fi) {
            int s = s0 + fi * 16 + g * 4;
            short4_t v;
#pragma unroll
            for (int e = 0; e < 4; ++e)
                v[e] = f2bf(fmaxf(acc[fi][fj][e], 0.f));
            *(short4_t*)(skb + (size_t)p * SKIP_CH + s) = v;
        }
    }
}

// end GEMM: out[(b*4096+p)*256+cls] = sum_s ewB[cls][s]*skipb[b][p][s] + eb[cls]
// 256 thr = 4 waves (2 cls x 2 p), tile 128 x 128, K = 512.
__global__ __launch_bounds__(256) void k_end_mfma(
    const short* __restrict__ skipB, const short* __restrict__ ewB,
    const float* __restrict__ eb, float* __restrict__ out)
{
    const int lane = threadIdx.x & 63;
    const int w    = threadIdx.x >> 6;
    const int wr   = w >> 1;            // 0..1
    const int wc   = w & 1;             // 0..1
    const int c0 = blockIdx.x * 128 + wr * 64;
    const int p0 = blockIdx.y * 128 + wc * 64;
    const int b  = blockIdx.z;

    const int r = lane & 15;
    const int g = lane >> 4;

    const short* skb = skipB + (size_t)b * OUTLEN * SKIP_CH;

    int aoff[4], boff[4];
#pragma unroll
    for (int fi = 0; fi < 4; ++fi)
        aoff[fi] = (c0 + fi * 16 + r) * SKIP_CH + g * 8;
#pragma unroll
    for (int fj = 0; fj < 4; ++fj)
        boff[fj] = (p0 + fj * 16 + r) * SKIP_CH + g * 8;

    f32x4 acc[4][4];
    const f32x4 zero4 = {0.f, 0.f, 0.f, 0.f};
#pragma unroll
    for (int fi = 0; fi < 4; ++fi)
#pragma unroll
        for (int fj = 0; fj < 4; ++fj) acc[fi][fj] = zero4;

    for (int kt = 0; kt < SKIP_CH / 32; ++kt) {
        bf16x8 av[4], bv[4];
#pragma unroll
        for (int fi = 0; fi < 4; ++fi)
            av[fi] = *(const bf16x8*)(ewB + aoff[fi] + kt * 32);
#pragma unroll
        for (int fj = 0; fj < 4; ++fj)
            bv[fj] = *(const bf16x8*)(skb + boff[fj] + kt * 32);
#pragma unroll
        for (int fi = 0; fi < 4; ++fi)
#pragma unroll
            for (int fj = 0; fj < 4; ++fj)
                acc[fi][fj] = __builtin_amdgcn_mfma_f32_16x16x32_bf16(
                    av[fi], bv[fj], acc[fi][fj], 0, 0, 0);
    }

#pragma unroll
    for (int fj = 0; fj < 4; ++fj) {
        int p = p0 + fj * 16 + r;
#pragma unroll
        for (int fi = 0; fi < 4; ++fi) {
            int cls = c0 + fi * 16 + g * 4;
            f32x4 bias = *(const f32x4*)(eb + cls);
            f32x4 v;
#pragma unroll
            for (int e = 0; e < 4; ++e) v[e] = acc[fi][fj][e] + bias[e];
            *(f32x4*)(out + ((size_t)b * OUTLEN + p) * CLASSES + cls) = v;
        }
    }
}

extern "C" void kernel_launch(void* const* d_in, const int* in_sizes, int n_in,
                              void* d_out, int out_size, void* d_ws, size_t ws_size,
                              hipStream_t stream) {
    const float* x   = (const float*)d_in[0];
    const float* sw  = (const float*)d_in[1];
    const float* fw  = (const float*)d_in[2];
    const float* gw  = (const float*)d_in[3];
    const float* rw  = (const float*)d_in[4];
    const float* wsk = (const float*)d_in[5];
    const float* ew  = (const float*)d_in[6];
    const float* eb  = (const float*)d_in[7];
    float* out = (float*)d_out;

    // workspace carve-up (~136 MB)
    float* h0 = (float*)d_ws;
    float* h1 = h0 + (size_t)BATCH * RES_CH * SEQ;
    short* Z     = (short*)(h1 + (size_t)BATCH * RES_CH * SEQ);
    short* skipb = Z + (size_t)BATCH * OUTLEN * QTOT;
    short* wskB  = skipb + (size_t)BATCH * OUTLEN * SKIP_CH;
    short* ewB   = wskB + (size_t)NLAYERS * SKIP_CH * DIL_CH;

    k_init<<<dim3((BATCH * SEQ + 255) / 256), 256, 0, stream>>>(x, sw, h0);
    k_cvt<<<dim3((NLAYERS * SKIP_CH * DIL_CH + 255) / 256), 256, 0, stream>>>(
        wsk, wskB, NLAYERS * SKIP_CH * DIL_CH);
    k_cvt<<<dim3((CLASSES * SKIP_CH + 255) / 256), 256, 0, stream>>>(
        ew, ewB, CLASSES * SKIP_CH);

    float* hbuf[2] = {h0, h1};
    int pmin = 0, cur = 0;
    for (int i = 0; i < NLAYERS; ++i) {
        int d = 1 << (i % 10);
        int pmin_out = pmin + d;
        int Lp = SEQ - pmin_out;
        dim3 g((Lp + 63) / 64, BATCH);
        k_layer2<<<g, 256, 0, stream>>>(hbuf[cur], hbuf[cur ^ 1], fw, gw, rw, Z,
                                        i, d, pmin_out);
        cur ^= 1;
        pmin = pmin_out;
    }

    k_skip_mfma<<<dim3(SKIP_CH / 128, OUTLEN / 256, BATCH), 512, 0, stream>>>(
        Z, wskB, skipb);
    k_end_mfma<<<dim3(CLASSES / 128, OUTLEN / 128, BATCH), 256, 0, stream>>>(
        skipb, ewB, eb, out);
}

// Round 3
// 553.805 us; speedup vs baseline: 5.3990x; 1.7710x over previous
//
#include <hip/hip_runtime.h>
#include <hip/hip_bf16.h>

// WaveNet on MI355X — round 3: MFMA everywhere + XCD-local skip GEMM.
//
// Layouts (p = original position in [0,8192)):
//   hf0/hf1 : [b][p][c] f32   residual stream (double-buffered)
//   hb0/hb1 : [b][p][c] bf16  shadow of hf (MFMA B-operand)
//   Z       : [b][p4][q] bf16, q = layer*32+o  (skip-GEMM K-contiguous)
//   skipb   : [b][p4][s] bf16 (relu applied)
//   wA      : [40][64 out(f0..31,g0..31)][64 k(tap0 c0..31, tap1 c0..31)] bf16
//   wR      : [40][32 c][32 o] bf16
//   wskB    : [40][512 s][32 o] bf16ографи (A-op, k-chunks contiguous per layer)
//   ewB     : [256 cls][512 s] bf16

#define BATCH   8
#define SEQ     8192
#define RES_CH  32
#define DIL_CH  32
#define SKIP_CH 512
#define CLASSES 256
#define NLAYERS 40
#define OUTLEN  4096
#define PSTART  (SEQ - OUTLEN)      // 4096
#define QTOT    (NLAYERS * DIL_CH)  // 1280

typedef __attribute__((ext_vector_type(8))) short bf16x8;
typedef __attribute__((ext_vector_type(4))) short short4_t;
typedef __attribute__((ext_vector_type(4))) float f32x4;

__device__ __forceinline__ float fast_sigmoid(float x) {
    return __builtin_amdgcn_rcpf(1.0f + __expf(-x));
}
__device__ __forceinline__ float fast_tanh(float x) {
    return 1.0f - 2.0f * __builtin_amdgcn_rcpf(1.0f + __expf(2.0f * x));
}
// f32 -> bf16 bits, round-to-nearest-even
__device__ __forceinline__ short f2bf(float x) {
    unsigned u = __float_as_uint(x);
    unsigned r = (u + 0x7fffu + ((u >> 16) & 1u)) >> 16;
    return (short)r;
}

// ---------------- prep kernels ----------------

// hf[b][p][c] = x[b][p]*sw[c]; hb = bf16(hf)
__global__ __launch_bounds__(256) void k_init(const float* __restrict__ x,
                                              const float* __restrict__ sw,
                                              float* __restrict__ hf,
                                              short* __restrict__ hb) {
    int idx = blockIdx.x * 256 + threadIdx.x;
    if (idx >= BATCH * SEQ) return;
    float v = x[idx];
    float* hp = hf + (size_t)idx * RES_CH;
    short* bp = hb + (size_t)idx * RES_CH;
#pragma unroll
    for (int c = 0; c < RES_CH; ++c) {
        float t = v * sw[c];
        hp[c] = t;
        bp[c] = f2bf(t);
    }
}

__global__ __launch_bounds__(256) void k_cvt(const float* __restrict__ src,
                                             short* __restrict__ dst, int n) {
    int i = blockIdx.x * 256 + threadIdx.x;
    if (i < n) dst[i] = f2bf(src[i]);
}

// wA[i][o][k]: o<32 -> filter out o, o>=32 -> gate out o-32; k<32 -> tap0 ch k,
// k>=32 -> tap1 ch k-32.  fw/gw are [i][o][c][2].
__global__ __launch_bounds__(256) void k_prep_wA(const float* __restrict__ fw,
                                                 const float* __restrict__ gw,
                                                 short* __restrict__ wA) {
    int idx = blockIdx.x * 256 + threadIdx.x;   // 40*64*64
    if (idx >= NLAYERS * 64 * 64) return;
    int k = idx & 63;
    int o = (idx >> 6) & 63;
    int i = idx >> 12;
    int tap = k >> 5, c = k & 31;
    float v = (o < 32) ? fw[((i * 32 + o) * 32 + c) * 2 + tap]
                       : gw[((i * 32 + (o - 32)) * 32 + c) * 2 + tap];
    wA[idx] = f2bf(v);
}

// ---------------- layer kernel (MFMA) ----------------
// Block = 256 thr = 4 waves; wave handles 32 positions.
// f/g GEMM: M=64 outs, K=64 (2 taps x 32 ch), N=32 pos -> acc[4][2].
// Activation lane-local (f at fi, g at fi+2). Res GEMM: M=32, K=32, C-in = h1.
__global__ __launch_bounds__(256) void k_layer_mfma(
    const float* __restrict__ hfin, const short* __restrict__ hbin,
    float* __restrict__ hfout, short* __restrict__ hbout,
    const short* __restrict__ wA, const short* __restrict__ wR,
    short* __restrict__ Z, int layer, int d, int pmin_out)
{
    __shared__ short zl[4][32][40];   // per-wave z tile [pos][o], stride 40 (80B, 16B-aligned)
    const int lane = threadIdx.x & 63;
    const int w    = threadIdx.x >> 6;
    const int r = lane & 15, g = lane >> 4;
    const int b = blockIdx.y;
    const int p0 = pmin_out + (blockIdx.x * 4 + w) * 32;

    const short* hb = hbin + (size_t)b * SEQ * RES_CH;
    const float* hf = hfin + (size_t)b * SEQ * RES_CH;

    int pl[2]; bool pv[2];
#pragma unroll
    for (int fj = 0; fj < 2; ++fj) {
        int p = p0 + fj * 16 + r;
        pv[fj] = p < SEQ;
        pl[fj] = pv[fj] ? p : SEQ - 1;   // clamp loads, guard stores
    }

    // A fragments (wave-uniform rows via r; L2-hot, 8KB/layer)
    const short* wAl = wA + layer * 4096;
    bf16x8 av[4][2];
#pragma unroll
    for (int fi = 0; fi < 4; ++fi)
#pragma unroll
        for (int kt = 0; kt < 2; ++kt)
            av[fi][kt] = *(const bf16x8*)(wAl + (fi * 16 + r) * 64 + kt * 32 + g * 8);

    // B fragments: kt=0 -> tap0 (p-d), kt=1 -> tap1 (p)
    bf16x8 bv[2][2];
#pragma unroll
    for (int fj = 0; fj < 2; ++fj) {
        bv[fj][0] = *(const bf16x8*)(hb + (size_t)(pl[fj] - d) * RES_CH + g * 8);
        bv[fj][1] = *(const bf16x8*)(hb + (size_t)pl[fj] * RES_CH + g * 8);
    }

    f32x4 acc[4][2];
    const f32x4 zero4 = {0.f, 0.f, 0.f, 0.f};
#pragma unroll
    for (int fi = 0; fi < 4; ++fi)
#pragma unroll
        for (int fj = 0; fj < 2; ++fj) acc[fi][fj] = zero4;

#pragma unroll
    for (int kt = 0; kt < 2; ++kt)
#pragma unroll
        for (int fi = 0; fi < 4; ++fi)
#pragma unroll
            for (int fj = 0; fj < 2; ++fj)
                acc[fi][fj] = __builtin_amdgcn_mfma_f32_16x16x32_bf16(
                    av[fi][kt], bv[fj][kt], acc[fi][fj], 0, 0, 0);

    // z = tanh(f)*sigmoid(g): acc[fi'] holds f, acc[fi'+2] holds g, same lane/reg.
    short4_t zb4[2][2];
#pragma unroll
    for (int fp = 0; fp < 2; ++fp)
#pragma unroll
        for (int fj = 0; fj < 2; ++fj) {
            short4_t v;
#pragma unroll
            for (int e = 0; e < 4; ++e) {
                float zf = fast_tanh(acc[fp][fj][e]) * fast_sigmoid(acc[fp + 2][fj][e]);
                v[e] = f2bf(zf);
            }
            zb4[fp][fj] = v;
        }

    // stash z for the skip GEMM (rows o = fp*16+g*4..+3, col p = fj*16+r)
#pragma unroll
    for (int fj = 0; fj < 2; ++fj)
        if (pv[fj] && pl[fj] >= PSTART) {
            short* zp = Z + ((size_t)b * OUTLEN + (pl[fj] - PSTART)) * QTOT + layer * DIL_CH;
#pragma unroll
            for (int fp = 0; fp < 2; ++fp)
                *(short4_t*)(zp + fp * 16 + g * 4) = zb4[fp][fj];
        }

    // z -> LDS for the res GEMM B-operand
#pragma unroll
    for (int fj = 0; fj < 2; ++fj)
#pragma unroll
        for (int fp = 0; fp < 2; ++fp)
            *(short4_t*)&zl[w][fj * 16 + r][fp * 16 + g * 4] = zb4[fp][fj];

    __syncthreads();

    bf16x8 avr[2], bvr[2];
#pragma unroll
    for (int fi = 0; fi < 2; ++fi)
        avr[fi] = *(const bf16x8*)(wR + layer * 1024 + (fi * 16 + r) * 32 + g * 8);
#pragma unroll
    for (int fj = 0; fj < 2; ++fj)
        bvr[fj] = *(const bf16x8*)&zl[w][fj * 16 + r][g * 8];

    // C-in = h1 (fp32) -> full-precision residual accumulation
    f32x4 racc[2][2];
#pragma unroll
    for (int fi = 0; fi < 2; ++fi)
#pragma unroll
        for (int fj = 0; fj < 2; ++fj)
            racc[fi][fj] = *(const f32x4*)(hf + (size_t)pl[fj] * RES_CH + fi * 16 + g * 4);

#pragma unroll
    for (int fi = 0; fi < 2; ++fi)
#pragma unroll
        for (int fj = 0; fj < 2; ++fj)
            racc[fi][fj] = __builtin_amdgcn_mfma_f32_16x16x32_bf16(
                avr[fi], bvr[fj], racc[fi][fj], 0, 0, 0);

    float* hfo = hfout + (size_t)b * SEQ * RES_CH;
    short* hbo = hbout + (size_t)b * SEQ * RES_CH;
#pragma unroll
    for (int fj = 0; fj < 2; ++fj)
        if (pv[fj]) {
#pragma unroll
            for (int fi = 0; fi < 2; ++fi) {
                *(f32x4*)(hfo + (size_t)pl[fj] * RES_CH + fi * 16 + g * 4) = racc[fi][fj];
                short4_t sv;
#pragma unroll
                for (int e = 0; e < 4; ++e) sv[e] = f2bf(racc[fi][fj][e]);
                *(short4_t*)(hbo + (size_t)pl[fj] * RES_CH + fi * 16 + g * 4) = sv;
            }
        }
}

// ---------------- skip GEMM ----------------
// C[s][p] = relu(sum_q wskB[s][q]*Z[b][p][q]) -> bf16 [b][p][s].
// 256 thr = 4 waves (2s x 2p), tile 128x128, K=1280 (40 steps), reg ping-pong
// prefetch. 1D grid, XCD-bijective swizzle: xcd = bid&7 owns batch b=xcd.
#define SK_LOAD(A, B, kt)                                                   \
    {                                                                       \
        _Pragma("unroll") for (int fi = 0; fi < 4; ++fi)                    \
            A[fi] = *(const bf16x8*)(wskB + aoff[fi] + (kt) * (SKIP_CH * 32)); \
        _Pragma("unroll") for (int fj = 0; fj < 4; ++fj)                    \
            B[fj] = *(const bf16x8*)(Zb + boff[fj] + (kt) * 32);            \
    }
#define SK_MFMA(A, B)                                                       \
    {                                                                       \
        _Pragma("unroll") for (int fi = 0; fi < 4; ++fi)                    \
            _Pragma("unroll") for (int fj = 0; fj < 4; ++fj)                \
                acc[fi][fj] = __builtin_amdgcn_mfma_f32_16x16x32_bf16(      \
                    A[fi], B[fj], acc[fi][fj], 0, 0, 0);                    \
    }

__global__ __launch_bounds__(256) void k_skip_mfma(
    const short* __restrict__ Z, const short* __restrict__ wskB,
    short* __restrict__ skipb)
{
    const int n = blockIdx.x;            // 1024 blocks
    const int b = n & 7;                 // one batch per XCD
    const int idx = n >> 3;              // 0..127: s fastest -> s-blocks of a
    const int sb = idx & 3;              //   p-tile are L2-adjacent
    const int pb = idx >> 2;             // 0..31
    const int lane = threadIdx.x & 63;
    const int w = threadIdx.x >> 6;
    const int s0 = sb * 128 + (w >> 1) * 64;
    const int p0 = pb * 128 + (w & 1) * 64;
    const int r = lane & 15, g = lane >> 4;

    const short* Zb = Z + (size_t)b * OUTLEN * QTOT;

    int aoff[4], boff[4];
#pragma unroll
    for (int fi = 0; fi < 4; ++fi) aoff[fi] = (s0 + fi * 16 + r) * 32 + g * 8;
#pragma unroll
    for (int fj = 0; fj < 4; ++fj) boff[fj] = (p0 + fj * 16 + r) * QTOT + g * 8;

    f32x4 acc[4][4];
    const f32x4 zero4 = {0.f, 0.f, 0.f, 0.f};
#pragma unroll
    for (int fi = 0; fi < 4; ++fi)
#pragma unroll
        for (int fj = 0; fj < 4; ++fj) acc[fi][fj] = zero4;

    bf16x8 a0[4], b0[4], a1[4], b1[4];
    SK_LOAD(a0, b0, 0)
#pragma unroll 1
    for (int kt = 0; kt + 2 < QTOT / 32; kt += 2) {
        SK_LOAD(a1, b1, kt + 1)
        SK_MFMA(a0, b0)
        SK_LOAD(a0, b0, kt + 2)
        SK_MFMA(a1, b1)
    }
    SK_LOAD(a1, b1, QTOT / 32 - 1)
    SK_MFMA(a0, b0)
    SK_MFMA(a1, b1)

    short* skb = skipb + (size_t)b * OUTLEN * SKIP_CH;
#pragma unroll
    for (int fj = 0; fj < 4; ++fj) {
        int p = p0 + fj * 16 + r;
#pragma unroll
        for (int fi = 0; fi < 4; ++fi) {
            int s = s0 + fi * 16 + g * 4;
            short4_t v;
#pragma unroll
            for (int e = 0; e < 4; ++e) v[e] = f2bf(fmaxf(acc[fi][fj][e], 0.f));
            *(short4_t*)(skb + (size_t)p * SKIP_CH + s) = v;
        }
    }
}

// ---------------- end GEMM ----------------
#define EK_LOAD(A, B, kt)                                                   \
    {                                                                       \
        _Pragma("unroll") for (int fi = 0; fi < 4; ++fi)                    \
            A[fi] = *(const bf16x8*)(ewB + aoff[fi] + (kt) * 32);           \
        _Pragma("unroll") for (int fj = 0; fj < 4; ++fj)                    \
            B[fj] = *(const bf16x8*)(skb + boff[fj] + (kt) * 32);           \
    }

__global__ __launch_bounds__(256) void k_end_mfma(
    const short* __restrict__ skipB, const short* __restrict__ ewB,
    const float* __restrict__ eb, float* __restrict__ out)
{
    const int n = blockIdx.x;            // 512 blocks
    const int b = n & 7;
    const int idx = n >> 3;              // 0..63
    const int cb = idx & 1;
    const int pb = idx >> 1;             // 0..31
    const int lane = threadIdx.x & 63;
    const int w = threadIdx.x >> 6;
    const int c0 = cb * 128 + (w >> 1) * 64;
    const int p0 = pb * 128 + (w & 1) * 64;
    const int r = lane & 15, g = lane >> 4;

    const short* skb = skipB + (size_t)b * OUTLEN * SKIP_CH;

    int aoff[4], boff[4];
#pragma unroll
    for (int fi = 0; fi < 4; ++fi) aoff[fi] = (c0 + fi * 16 + r) * SKIP_CH + g * 8;
#pragma unroll
    for (int fj = 0; fj < 4; ++fj) boff[fj] = (p0 + fj * 16 + r) * SKIP_CH + g * 8;

    f32x4 acc[4][4];
    const f32x4 zero4 = {0.f, 0.f, 0.f, 0.f};
#pragma unroll
    for (int fi = 0; fi < 4; ++fi)
#pragma unroll
        for (int fj = 0; fj < 4; ++fj) acc[fi][fj] = zero4;

    bf16x8 a0[4], b0[4], a1[4], b1[4];
    EK_LOAD(a0, b0, 0)
#pragma unroll 1
    for (int kt = 0; kt + 2 < SKIP_CH / 32; kt += 2) {
        EK_LOAD(a1, b1, kt + 1)
        SK_MFMA(a0, b0)
        EK_LOAD(a0, b0, kt + 2)
        SK_MFMA(a1, b1)
    }
    EK_LOAD(a1, b1, SKIP_CH / 32 - 1)
    SK_MFMA(a0, b0)
    SK_MFMA(a1, b1)

#pragma unroll
    for (int fj = 0; fj < 4; ++fj) {
        int p = p0 + fj * 16 + r;
#pragma unroll
        for (int fi = 0; fi < 4; ++fi) {
            int cls = c0 + fi * 16 + g * 4;
            f32x4 bias = *(const f32x4*)(eb + cls);
            f32x4 v;
#pragma unroll
            for (int e = 0; e < 4; ++e) v[e] = acc[fi][fj][e] + bias[e];
            *(f32x4*)(out + ((size_t)b * OUTLEN + p) * CLASSES + cls) = v;
        }
    }
}

extern "C" void kernel_launch(void* const* d_in, const int* in_sizes, int n_in,
                              void* d_out, int out_size, void* d_ws, size_t ws_size,
                              hipStream_t stream) {
    const float* x   = (const float*)d_in[0];
    const float* sw  = (const float*)d_in[1];
    const float* fw  = (const float*)d_in[2];
    const float* gw  = (const float*)d_in[3];
    const float* rw  = (const float*)d_in[4];
    const float* wsk = (const float*)d_in[5];
    const float* ew  = (const float*)d_in[6];
    const float* eb  = (const float*)d_in[7];
    float* out = (float*)d_out;

    const size_t HN = (size_t)BATCH * SEQ * RES_CH;   // 2097152
    float* hf0 = (float*)d_ws;
    float* hf1 = hf0 + HN;
    short* hb0 = (short*)(hf1 + HN);
    short* hb1 = hb0 + HN;
    short* Z     = hb1 + HN;                              // 8*4096*1280
    short* skipb = Z + (size_t)BATCH * OUTLEN * QTOT;     // 8*4096*512
    short* wA    = skipb + (size_t)BATCH * OUTLEN * SKIP_CH;  // 40*64*64
    short* wR    = wA + NLAYERS * 64 * 64;                // 40*32*32
    short* wskB  = wR + NLAYERS * 32 * 32;                // 40*512*32
    short* ewB   = wskB + NLAYERS * SKIP_CH * DIL_CH;     // 256*512
    // total ~145 MB

    k_init<<<dim3((BATCH * SEQ + 255) / 256), 256, 0, stream>>>(x, sw, hf0, hb0);
    k_prep_wA<<<dim3(NLAYERS * 64 * 64 / 256), 256, 0, stream>>>(fw, gw, wA);
    k_cvt<<<dim3((NLAYERS * 32 * 32 + 255) / 256), 256, 0, stream>>>(rw, wR, NLAYERS * 32 * 32);
    k_cvt<<<dim3((NLAYERS * SKIP_CH * DIL_CH + 255) / 256), 256, 0, stream>>>(
        wsk, wskB, NLAYERS * SKIP_CH * DIL_CH);
    k_cvt<<<dim3((CLASSES * SKIP_CH + 255) / 256), 256, 0, stream>>>(
        ew, ewB, CLASSES * SKIP_CH);

    float* hf[2] = {hf0, hf1};
    short* hb[2] = {hb0, hb1};
    int pmin = 0, cur = 0;
    for (int i = 0; i < NLAYERS; ++i) {
        int d = 1 << (i % 10);
        int pmin_out = pmin + d;
        int Lp = SEQ - pmin_out;
        dim3 grd((Lp + 127) / 128, BATCH);
        k_layer_mfma<<<grd, 256, 0, stream>>>(hf[cur], hb[cur], hf[cur ^ 1], hb[cur ^ 1],
                                              wA, wR, Z, i, d, pmin_out);
        cur ^= 1;
        pmin = pmin_out;
    }

    k_skip_mfma<<<dim3(1024), 256, 0, stream>>>(Z, wskB, skipb);
    k_end_mfma<<<dim3(512), 256, 0, stream>>>(skipb, ewB, eb, out);
}